// Round 3
// baseline (6350.763 us; speedup 1.0000x reference)
//
#include <hip/hip_runtime.h>
#include <hip/hip_bf16.h>

#define B_    64
#define NP_   196
#define NVIS_ 49
#define D_    384
#define DD_   256
#define SENC_ 50
#define SDEC_ 196

typedef __hip_bfloat16 bf16;
__device__ __forceinline__ float bf2f(bf16 x) { return __bfloat162float(x); }
__device__ __forceinline__ bf16 f2bf(float x) { return __float2bfloat16(x); }

// Read input element i from a d_in array whose dtype is resolved at runtime:
// f==1 -> fp32, f==0 -> bf16. Element index is dtype-independent.
__device__ __forceinline__ float rdin(const void* p, long i, int f) {
  return f ? ((const float*)p)[i] : bf2f(((const bf16*)p)[i]);
}

// ---- dtype probe: conv_w ~ N(0, 0.02). Read first 512 entries AS bf16.
// If the underlying data is fp32, half of those "bf16" values are fp32 low
// mantissa halves -> random exponents -> max huge. If truly bf16, max ~0.1.
__global__ void probe_kernel(const void* w, int* flag) {
  int tid = threadIdx.x;
  float mx = 0.f;
  for (int i = tid; i < 512; i += 64)
    mx = fmaxf(mx, fabsf(bf2f(((const bf16*)w)[i])));
#pragma unroll
  for (int off = 32; off; off >>= 1) mx = fmaxf(mx, __shfl_xor(mx, off));
  if (tid == 0) *flag = (mx > 1e3f) ? 1 : 0;  // 1 => inputs are fp32
}

// ---- diagnostic fill (ws too small): encode MB count, finite & readable ----
__global__ __launch_bounds__(256) void fill_kernel(bf16* out, float v, int n) {
  int idx = blockIdx.x * 256 + threadIdx.x;
  if (idx < n) out[idx] = f2bf(v);
}

// ---------------- im2col over VISIBLE patches only -> fp32 ----------------
__global__ __launch_bounds__(256) void im2col_vis_kernel(
    const void* __restrict__ x, const int* __restrict__ unmasked,
    float* __restrict__ out, const int* __restrict__ dflag) {
  int f = *dflag;
  int idx = blockIdx.x * 256 + threadIdx.x;
  const int TOT = B_ * NVIS_ * 768;
  if (idx >= TOT) return;
  int k = idx % 768;
  int row = idx / 768;
  int j = row % NVIS_;
  int b = row / NVIS_;
  int n = unmasked[b * NVIS_ + j];
  int ph = n / 14, pw = n % 14;
  int c  = k >> 8;
  int rr = (k >> 4) & 15;
  int cc = k & 15;
  out[idx] = rdin(x, (long)(((b * 3 + c) * 224) + ph * 16 + rr) * 224 + pw * 16 + cc, f);
}

// ---- GEMM: C[M,N] = epi(A[M,K](f32) @ W[N,K](input dtype)^T + bias) --------
// MODE 0: plain  MODE 1: exact GELU  MODE 2: += res (f32)
// out_mode: 1 -> f32 store, 2 -> store per input dtype (f32 if flag else bf16)
template <int MODE>
__global__ __launch_bounds__(256) void gemm_kernel(
    const float* __restrict__ A, const void* __restrict__ W, long wOff,
    const void* __restrict__ bias, long bOff, const float* __restrict__ res,
    void* __restrict__ C, int M, int N, int K, int out_mode,
    const int* __restrict__ dflag) {
  int f = *dflag;
  __shared__ float As[16][68];
  __shared__ float Bs[16][68];
  int tid = threadIdx.x;
  int tx = tid & 15, ty = tid >> 4;
  int bx = blockIdx.x, by = blockIdx.y;
  const float* Ab = A + (long)by * 64 * K;
  long wBase = wOff + (long)bx * 64 * K;
  float acc[4][4] = {};
  int c = tid & 15;
  int r = tid >> 4;
  for (int k0 = 0; k0 < K; k0 += 16) {
#pragma unroll
    for (int it = 0; it < 4; it++) {
      int m = r + 16 * it;
      As[c][m] = Ab[(long)m * K + k0 + c];
      Bs[c][m] = rdin(W, wBase + (long)m * K + k0 + c, f);
    }
    __syncthreads();
#pragma unroll
    for (int k = 0; k < 16; k++) {
      float4 a4 = *(const float4*)&As[k][ty * 4];
      float4 b4 = *(const float4*)&Bs[k][tx * 4];
      float av[4] = {a4.x, a4.y, a4.z, a4.w};
      float bv[4] = {b4.x, b4.y, b4.z, b4.w};
#pragma unroll
      for (int i = 0; i < 4; i++)
#pragma unroll
        for (int j = 0; j < 4; j++) acc[i][j] += av[i] * bv[j];
    }
    __syncthreads();
  }
  int om = (out_mode == 2) ? (f ? 1 : 0) : 1;  // 1=f32 store, 0=bf16 store
#pragma unroll
  for (int i = 0; i < 4; i++) {
    int cm = by * 64 + ty * 4 + i;
#pragma unroll
    for (int j = 0; j < 4; j++) {
      int cn = bx * 64 + tx * 4 + j;
      float v = acc[i][j] + rdin(bias, bOff + cn, f);
      if constexpr (MODE == 1) v = 0.5f * v * (1.0f + erff(v * 0.70710678f));
      if constexpr (MODE == 2) v += res[(long)cm * N + cn];
      if (om) ((float*)C)[(long)cm * N + cn] = v;
      else    ((bf16*)C)[(long)cm * N + cn] = f2bf(v);
    }
  }
}

// ---------------- LayerNorm: one wave per row, f32 -> f32 ----------------
template <int N>
__global__ __launch_bounds__(256) void ln_kernel(
    const float* __restrict__ X, const void* __restrict__ w, long wOff,
    const void* __restrict__ bv, long bOff, float* __restrict__ Y, int M,
    const int* __restrict__ dflag) {
  int f = *dflag;
  int row = blockIdx.x * 4 + (threadIdx.x >> 6);
  int lane = threadIdx.x & 63;
  if (row >= M) return;
  const float* xr = X + (long)row * N;
  constexpr int CNT = N / 64;
  float v[CNT];
  float sum = 0.f;
#pragma unroll
  for (int i = 0; i < CNT; i++) { v[i] = xr[lane + 64 * i]; sum += v[i]; }
#pragma unroll
  for (int off = 32; off; off >>= 1) sum += __shfl_xor(sum, off);
  float mean = sum * (1.0f / N);
  float vs = 0.f;
#pragma unroll
  for (int i = 0; i < CNT; i++) { float d = v[i] - mean; vs += d * d; }
#pragma unroll
  for (int off = 32; off; off >>= 1) vs += __shfl_xor(vs, off);
  float rstd = rsqrtf(vs * (1.0f / N) + 1e-5f);
  float* yr = Y + (long)row * N;
#pragma unroll
  for (int i = 0; i < CNT; i++) {
    int cidx = lane + 64 * i;
    yr[cidx] = (v[i] - mean) * rstd * rdin(w, wOff + cidx, f) + rdin(bv, bOff + cidx, f);
  }
}

// ---------------- flash attention: one thread per q-row (f32 io) ----------
template <int DH>
__global__ __launch_bounds__(64) void attn_kernel(
    const float* __restrict__ qkv, float* __restrict__ out,
    int S, int H, float scale) {
  int b = blockIdx.x / H, h = blockIdx.x % H;
  int tid = threadIdx.x;
  int q_row = blockIdx.y * 64 + tid;
  extern __shared__ float lds[];
  float* Ks = lds;
  float* Vs = lds + S * DH;
  int Dm = H * DH, tri = 3 * Dm;
  const float* base = qkv + (long)b * S * tri;
  for (int idx = tid; idx < S * DH; idx += 64) {
    int s = idx / DH, d = idx % DH;
    Ks[idx] = base[(long)s * tri + Dm + h * DH + d];
    Vs[idx] = base[(long)s * tri + 2 * Dm + h * DH + d];
  }
  __syncthreads();
  if (q_row >= S) return;
  float q[DH], o[DH];
#pragma unroll
  for (int d = 0; d < DH; d++) {
    q[d] = base[(long)q_row * tri + h * DH + d] * scale;
    o[d] = 0.f;
  }
  float m = -1e30f, l = 0.f;
  for (int j = 0; j < S; j++) {
    float s = 0.f;
#pragma unroll
    for (int d = 0; d < DH; d++) s += q[d] * Ks[j * DH + d];
    float mn = fmaxf(m, s);
    float corr = __expf(m - mn);
    float p = __expf(s - mn);
    l = l * corr + p;
    m = mn;
#pragma unroll
    for (int d = 0; d < DH; d++) o[d] = o[d] * corr + p * Vs[j * DH + d];
  }
  float inv = 1.f / l;
  float* op = out + ((long)(b * S + q_row) * Dm + h * DH);
#pragma unroll
  for (int d = 0; d < DH; d++) op[d] = o[d] * inv;
}

// ---------------- small elementwise kernels ----------------
__global__ __launch_bounds__(256) void build_xe_kernel(
    const float* __restrict__ vis, const void* __restrict__ cls,
    const void* __restrict__ pos, const int* __restrict__ unmasked,
    float* __restrict__ xe, const int* __restrict__ dflag) {
  int f = *dflag;
  int idx = blockIdx.x * 256 + threadIdx.x;
  const int TOT = B_ * SENC_ * D_;
  if (idx >= TOT) return;
  int d = idx % D_;
  int s = (idx / D_) % SENC_;
  int b = idx / (D_ * SENC_);
  float v;
  if (s == 0) {
    v = rdin(cls, d, f) + rdin(pos, d, f);
  } else {
    int j = s - 1;
    int n = unmasked[b * NVIS_ + j];
    v = vis[(long)(b * NVIS_ + j) * D_ + d] + rdin(pos, (long)(1 + n) * D_ + d, f);
  }
  xe[idx] = v;
}

__global__ __launch_bounds__(256) void dec_init_kernel(
    const void* __restrict__ mask_token, const void* __restrict__ dpos,
    float* __restrict__ full, const int* __restrict__ dflag) {
  int f = *dflag;
  int idx = blockIdx.x * 256 + threadIdx.x;
  const int TOT = B_ * NP_ * DD_;
  if (idx >= TOT) return;
  int d = idx % DD_;
  int n = (idx / DD_) % NP_;
  full[idx] = rdin(mask_token, d, f) + rdin(dpos, (long)(1 + n) * DD_ + d, f);
}

__global__ __launch_bounds__(256) void dec_scatter_kernel(
    const float* __restrict__ xd, const int* __restrict__ unmasked,
    const void* __restrict__ dpos, float* __restrict__ full,
    const int* __restrict__ dflag) {
  int f = *dflag;
  int idx = blockIdx.x * 256 + threadIdx.x;
  const int TOT = B_ * NVIS_ * DD_;
  if (idx >= TOT) return;
  int d = idx % DD_;
  int j = (idx / DD_) % NVIS_;
  int b = idx / (DD_ * NVIS_);
  int n = unmasked[b * NVIS_ + j];
  full[((long)(b * NP_ + n)) * DD_ + d] =
      xd[((long)(b * SENC_ + 1 + j)) * DD_ + d] + rdin(dpos, (long)(1 + n) * DD_ + d, f);
}

// ---------------- host ----------------
extern "C" void kernel_launch(void* const* d_in, const int* in_sizes, int n_in,
                              void* d_out, int out_size, void* d_ws, size_t ws_size,
                              hipStream_t stream) {
  (void)in_sizes; (void)n_in;
  const int* unmasked = (const int*)d_in[1];
  const int M_ENC = B_ * SENC_;  // 3200
  const int M_DEC = B_ * NP_;    // 12544
  const int M_VIS = B_ * NVIS_;  // 3136

  // ---- fp32 workspace layout ----
  // big  [0, 51,380,224)            12544*1024 f32
  //   im2col alias [0, 9,633,792)   3136*768 f32
  //   vis alias [12,582,912, 17,399,808)  3136*384 f32
  //   xd alias  [0, 3,276,800)      3200*256 f32 (post-encoder)
  // t0   [51,380,224, 64,225,280)   12544*256 f32
  // xe   [64,225,280, 69,140,480)   3200*384 f32
  // full [69,140,480, 81,985,536)   12544*256 f32
  // flag [81,985,536, 81,985,540)
  const size_t NEEDED = 81985540;
  if (ws_size < NEEDED) {  // diagnostic: encode ws MB in the output, finite
    fill_kernel<<<(out_size + 255) / 256, 256, 0, stream>>>(
        (bf16*)d_out, (float)(ws_size >> 20), out_size);
    return;
  }
  char* wsb = (char*)d_ws;
  float* big    = (float*)wsb;
  float* im2col = big;
  float* vis    = (float*)(wsb + 12582912);
  float* xd     = (float*)wsb;
  float* t0     = (float*)(wsb + 51380224);
  float* xe     = (float*)(wsb + 64225280);
  float* full   = (float*)(wsb + 69140480);
  int*   dflag  = (int*)(wsb + 81985536);

  probe_kernel<<<1, 64, 0, stream>>>(d_in[3], dflag);

  auto gemm = [&](int mode, const float* A, const void* W, long wOff,
                  const void* bias, long bOff, const float* res, void* C,
                  int M, int N, int K, int out_mode) {
    dim3 g(N / 64, M / 64);
    if (mode == 0)
      gemm_kernel<0><<<g, 256, 0, stream>>>(A, W, wOff, bias, bOff, res, C, M, N, K, out_mode, dflag);
    else if (mode == 1)
      gemm_kernel<1><<<g, 256, 0, stream>>>(A, W, wOff, bias, bOff, res, C, M, N, K, out_mode, dflag);
    else
      gemm_kernel<2><<<g, 256, 0, stream>>>(A, W, wOff, bias, bOff, res, C, M, N, K, out_mode, dflag);
  };

  // ---- patchify (visible patches only) ----
  {
    int tot = M_VIS * 768;
    im2col_vis_kernel<<<(tot + 255) / 256, 256, 0, stream>>>(d_in[0], unmasked, im2col, dflag);
    gemm(0, im2col, d_in[3], 0, d_in[4], 0, nullptr, vis, M_VIS, D_, 768, 1);
    int tot2 = B_ * SENC_ * D_;
    build_xe_kernel<<<(tot2 + 255) / 256, 256, 0, stream>>>(vis, d_in[5], d_in[6], unmasked, xe, dflag);
  }

  // ---- encoder: 6 blocks, S=50, D=384, H=6, dh=64 ----
  for (int i = 0; i < 6; i++) {
    ln_kernel<D_><<<M_ENC / 4, 256, 0, stream>>>(xe, d_in[7], (long)i * D_, d_in[8], (long)i * D_, t0, M_ENC, dflag);
    gemm(0, t0, d_in[9], (long)i * 3 * D_ * D_, d_in[10], (long)i * 3 * D_, nullptr, big, M_ENC, 3 * D_, D_, 1);
    attn_kernel<64><<<dim3(B_ * 6, 1), 64, 2 * SENC_ * 64 * 4, stream>>>(big, t0, SENC_, 6, 0.125f);
    gemm(2, t0, d_in[11], (long)i * D_ * D_, d_in[12], (long)i * D_, xe, xe, M_ENC, D_, D_, 1);
    ln_kernel<D_><<<M_ENC / 4, 256, 0, stream>>>(xe, d_in[13], (long)i * D_, d_in[14], (long)i * D_, t0, M_ENC, dflag);
    gemm(1, t0, d_in[15], (long)i * 4 * D_ * D_, d_in[16], (long)i * 4 * D_, nullptr, big, M_ENC, 4 * D_, D_, 1);
    gemm(2, big, d_in[17], (long)i * D_ * 4 * D_, d_in[18], (long)i * D_, xe, xe, M_ENC, D_, 4 * D_, 1);
  }
  ln_kernel<D_><<<M_ENC / 4, 256, 0, stream>>>(xe, d_in[19], 0, d_in[20], 0, t0, M_ENC, dflag);
  gemm(0, t0, d_in[21], 0, d_in[22], 0, nullptr, xd, M_ENC, DD_, D_, 1);

  // ---- assemble decoder input ----
  {
    int tot = B_ * NP_ * DD_;
    dec_init_kernel<<<(tot + 255) / 256, 256, 0, stream>>>(d_in[23], d_in[24], full, dflag);
    int tot2 = B_ * NVIS_ * DD_;
    dec_scatter_kernel<<<(tot2 + 255) / 256, 256, 0, stream>>>(xd, unmasked, d_in[24], full, dflag);
  }

  // ---- decoder: 4 blocks, S=196, D=256, H=8, dh=32 ----
  for (int i = 0; i < 4; i++) {
    ln_kernel<DD_><<<M_DEC / 4, 256, 0, stream>>>(full, d_in[25], (long)i * DD_, d_in[26], (long)i * DD_, t0, M_DEC, dflag);
    gemm(0, t0, d_in[27], (long)i * 3 * DD_ * DD_, d_in[28], (long)i * 3 * DD_, nullptr, big, M_DEC, 3 * DD_, DD_, 1);
    attn_kernel<32><<<dim3(B_ * 8, 4), 64, 2 * SDEC_ * 32 * 4, stream>>>(big, t0, SDEC_, 8, 0.17677669529663687f);
    gemm(2, t0, d_in[29], (long)i * DD_ * DD_, d_in[30], (long)i * DD_, full, full, M_DEC, DD_, DD_, 1);
    ln_kernel<DD_><<<M_DEC / 4, 256, 0, stream>>>(full, d_in[31], (long)i * DD_, d_in[32], (long)i * DD_, t0, M_DEC, dflag);
    gemm(1, t0, d_in[33], (long)i * 4 * DD_ * DD_, d_in[34], (long)i * 4 * DD_, nullptr, big, M_DEC, 4 * DD_, DD_, 1);
    gemm(2, big, d_in[35], (long)i * DD_ * 4 * DD_, d_in[36], (long)i * DD_, full, full, M_DEC, DD_, 4 * DD_, 1);
  }
  ln_kernel<DD_><<<M_DEC / 4, 256, 0, stream>>>(full, d_in[37], 0, d_in[38], 0, t0, M_DEC, dflag);

  // ---- predictor head: store dtype follows input dtype (out_mode=2) ----
  gemm(0, t0, d_in[39], 0, d_in[40], 0, nullptr, d_out, M_DEC, 768, DD_, 2);
}

// Round 4
// 2299.974 us; speedup vs baseline: 2.7612x; 2.7612x over previous
//
#include <hip/hip_runtime.h>
#include <hip/hip_bf16.h>

#define B_    64
#define NP_   196
#define NVIS_ 49
#define D_    384
#define DD_   256
#define SENC_ 50
#define SDEC_ 196

typedef __hip_bfloat16 bf16;
typedef __attribute__((ext_vector_type(8))) short short8;
typedef __attribute__((ext_vector_type(4))) float float4v;

__device__ __forceinline__ float bf2f(bf16 x) { return __bfloat162float(x); }
__device__ __forceinline__ bf16 f2bf(float x) { return __float2bfloat16(x); }
__device__ __forceinline__ float rdin(const void* p, long i, int f) {
  return f ? ((const float*)p)[i] : bf2f(((const bf16*)p)[i]);
}

// ---- dtype probe: conv_w ~ N(0,0.02). If data is fp32 read as bf16, the
// mantissa halves have random exponents -> huge max. ----
__global__ void probe_kernel(const void* w, int* flag) {
  int tid = threadIdx.x;
  float mx = 0.f;
  for (int i = tid; i < 512; i += 64)
    mx = fmaxf(mx, fabsf(bf2f(((const bf16*)w)[i])));
#pragma unroll
  for (int off = 32; off; off >>= 1) mx = fmaxf(mx, __shfl_xor(mx, off));
  if (tid == 0) *flag = (mx > 1e3f) ? 1 : 0;  // 1 => inputs are fp32
}

__global__ __launch_bounds__(256) void fill_kernel(bf16* out, float v, int n) {
  int idx = blockIdx.x * 256 + threadIdx.x;
  if (idx < n) out[idx] = f2bf(v);
}

// ---------------- im2col over VISIBLE patches only -> bf16 ----------------
__global__ __launch_bounds__(256) void im2col_vis_kernel(
    const void* __restrict__ x, const int* __restrict__ unmasked,
    bf16* __restrict__ out, const int* __restrict__ dflag) {
  int f = *dflag;
  int idx = blockIdx.x * 256 + threadIdx.x;
  const int TOT = B_ * NVIS_ * 768;
  if (idx >= TOT) return;
  int k = idx % 768;
  int row = idx / 768;
  int j = row % NVIS_;
  int b = row / NVIS_;
  int n = unmasked[b * NVIS_ + j];
  int ph = n / 14, pw = n % 14;
  int c  = k >> 8;
  int rr = (k >> 4) & 15;
  int cc = k & 15;
  out[idx] = f2bf(rdin(x, (long)(((b * 3 + c) * 224) + ph * 16 + rr) * 224 + pw * 16 + cc, f));
}

// ---- MFMA GEMM: C[M,N] = epi(A[M,K](bf16) @ W[N,K]^T + bias) --------------
// 128x128 tile, BK=32, 4 waves (2x2 of 64x64), v_mfma_f32_16x16x32_bf16.
// MODE 0 plain, 1 exact GELU, 2 += res(f32).
// out_mode: 0 bf16 store, 1 f32 store, 2 per dtype flag.
// M%128==0, N%128==0, K%32==0.
#define LDK 40
template <int MODE>
__global__ __launch_bounds__(256) void gemm_kernel(
    const bf16* __restrict__ A, const void* __restrict__ W, long wOff,
    const void* __restrict__ bias, long bOff, const float* __restrict__ res,
    void* __restrict__ C, int M, int N, int K, int out_mode,
    const int* __restrict__ dflag) {
  int f = *dflag;
  __shared__ bf16 Asl[128 * LDK];
  __shared__ bf16 Bsl[128 * LDK];
  int tid = threadIdx.x;
  int bx = blockIdx.x, by = blockIdx.y;
  int w = tid >> 6, lane = tid & 63;
  int quad = lane >> 4, l16 = lane & 15;
  int wm = (w & 1) * 64, wn = (w >> 1) * 64;
  int tr = tid >> 2, tc = (tid & 3) * 8;  // staging: rows tr,tr+64, 8 cols
  const bf16* Ab = A + (long)by * 128 * K;
  long wBase = wOff + (long)bx * 128 * K;

  float4v acc[4][4];
#pragma unroll
  for (int i = 0; i < 4; i++)
#pragma unroll
    for (int j = 0; j < 4; j++) acc[i][j] = (float4v){0.f, 0.f, 0.f, 0.f};

  for (int k0 = 0; k0 < K; k0 += 32) {
    // stage A (bf16 source)
#pragma unroll
    for (int h = 0; h < 2; h++) {
      int r = tr + h * 64;
      uint4 v = *(const uint4*)(Ab + (long)r * K + k0 + tc);
      *(uint4*)(&Asl[r * LDK + tc]) = v;
    }
    // stage W (runtime dtype)
    if (f) {
#pragma unroll
      for (int h = 0; h < 2; h++) {
        int r = tr + h * 64;
        const float* p = (const float*)W + wBase + (long)r * K + k0 + tc;
        float4 v0 = *(const float4*)p;
        float4 v1 = *(const float4*)(p + 4);
        union { uint4 u; bf16 hh[8]; } pk;
        pk.hh[0] = f2bf(v0.x); pk.hh[1] = f2bf(v0.y);
        pk.hh[2] = f2bf(v0.z); pk.hh[3] = f2bf(v0.w);
        pk.hh[4] = f2bf(v1.x); pk.hh[5] = f2bf(v1.y);
        pk.hh[6] = f2bf(v1.z); pk.hh[7] = f2bf(v1.w);
        *(uint4*)(&Bsl[r * LDK + tc]) = pk.u;
      }
    } else {
#pragma unroll
      for (int h = 0; h < 2; h++) {
        int r = tr + h * 64;
        uint4 v = *(const uint4*)((const bf16*)W + wBase + (long)r * K + k0 + tc);
        *(uint4*)(&Bsl[r * LDK + tc]) = v;
      }
    }
    __syncthreads();
    short8 af[4], bfr[4];
#pragma unroll
    for (int mi = 0; mi < 4; mi++)
      af[mi] = *(const short8*)&Asl[(wm + mi * 16 + l16) * LDK + quad * 8];
#pragma unroll
    for (int ni = 0; ni < 4; ni++)
      bfr[ni] = *(const short8*)&Bsl[(wn + ni * 16 + l16) * LDK + quad * 8];
#pragma unroll
    for (int mi = 0; mi < 4; mi++)
#pragma unroll
      for (int ni = 0; ni < 4; ni++)
        acc[mi][ni] = __builtin_amdgcn_mfma_f32_16x16x32_bf16(
            af[mi], bfr[ni], acc[mi][ni], 0, 0, 0);
    __syncthreads();
  }

  int om = (out_mode == 2) ? (f ? 1 : 0) : out_mode;  // 1=f32, 0=bf16
#pragma unroll
  for (int mi = 0; mi < 4; mi++) {
#pragma unroll
    for (int ni = 0; ni < 4; ni++) {
      int cn = bx * 128 + wn + ni * 16 + l16;
      float bval = rdin(bias, bOff + cn, f);
#pragma unroll
      for (int r = 0; r < 4; r++) {
        int cm = by * 128 + wm + mi * 16 + quad * 4 + r;
        float v = acc[mi][ni][r] + bval;
        if constexpr (MODE == 1) v = 0.5f * v * (1.0f + erff(v * 0.70710678f));
        if constexpr (MODE == 2) v += res[(long)cm * N + cn];
        if (om) ((float*)C)[(long)cm * N + cn] = v;
        else    ((bf16*)C)[(long)cm * N + cn] = f2bf(v);
      }
    }
  }
}

// ---------------- LayerNorm: one wave per row, f32 -> bf16 ----------------
template <int N>
__global__ __launch_bounds__(256) void ln_kernel(
    const float* __restrict__ X, const void* __restrict__ w, long wOff,
    const void* __restrict__ bv, long bOff, bf16* __restrict__ Y, int M,
    const int* __restrict__ dflag) {
  int f = *dflag;
  int row = blockIdx.x * 4 + (threadIdx.x >> 6);
  int lane = threadIdx.x & 63;
  if (row >= M) return;
  const float* xr = X + (long)row * N;
  constexpr int CNT = N / 64;
  float v[CNT];
  float sum = 0.f;
#pragma unroll
  for (int i = 0; i < CNT; i++) { v[i] = xr[lane + 64 * i]; sum += v[i]; }
#pragma unroll
  for (int off = 32; off; off >>= 1) sum += __shfl_xor(sum, off);
  float mean = sum * (1.0f / N);
  float vs = 0.f;
#pragma unroll
  for (int i = 0; i < CNT; i++) { float d = v[i] - mean; vs += d * d; }
#pragma unroll
  for (int off = 32; off; off >>= 1) vs += __shfl_xor(vs, off);
  float rstd = rsqrtf(vs * (1.0f / N) + 1e-5f);
  bf16* yr = Y + (long)row * N;
#pragma unroll
  for (int i = 0; i < CNT; i++) {
    int cidx = lane + 64 * i;
    yr[cidx] = f2bf((v[i] - mean) * rstd * rdin(w, wOff + cidx, f) + rdin(bv, bOff + cidx, f));
  }
}

// ---- decoder attention: S=196, DH=32, H=8. 256 thr, wave w rows w*49+lane.
__global__ __launch_bounds__(256) void attn_dec_kernel(
    const bf16* __restrict__ qkv, bf16* __restrict__ out) {
  const int S = SDEC_, H = 8, DH = 32, Dm = H * DH, tri = 3 * Dm;
  int b = blockIdx.x / H, h = blockIdx.x % H;
  int tid = threadIdx.x;
  __shared__ float Ks[SDEC_ * 32];
  __shared__ float Vs[SDEC_ * 32];
  const bf16* base = qkv + (long)b * S * tri;
  for (int idx = tid; idx < S * 4; idx += 256) {
    int s = idx >> 2, part = (idx & 3) * 8;
    union { uint4 u; bf16 hh[8]; } kk, vv;
    kk.u = *(const uint4*)(base + (long)s * tri + Dm + h * DH + part);
    vv.u = *(const uint4*)(base + (long)s * tri + 2 * Dm + h * DH + part);
#pragma unroll
    for (int j = 0; j < 8; j++) {
      Ks[s * DH + part + j] = bf2f(kk.hh[j]);
      Vs[s * DH + part + j] = bf2f(vv.hh[j]);
    }
  }
  __syncthreads();
  int w = tid >> 6, lane = tid & 63;
  int row = w * 49 + lane;
  if (lane >= 49) return;
  const float scale = 0.17677669529663687f;
  float q[DH], o[DH];
#pragma unroll
  for (int d = 0; d < DH; d++) {
    q[d] = bf2f(base[(long)row * tri + h * DH + d]) * scale;
    o[d] = 0.f;
  }
  float m = -1e30f, l = 0.f;
  for (int j = 0; j < S; j++) {
    float s = 0.f;
#pragma unroll
    for (int d = 0; d < DH; d++) s += q[d] * Ks[j * DH + d];
    float mn = fmaxf(m, s);
    float corr = __expf(m - mn);
    float p = __expf(s - mn);
    l = l * corr + p;
    m = mn;
#pragma unroll
    for (int d = 0; d < DH; d++) o[d] = o[d] * corr + p * Vs[j * DH + d];
  }
  float inv = 1.f / l;
  bf16* op = out + ((long)(b * S + row) * Dm + h * DH);
#pragma unroll
  for (int d = 0; d < DH; d++) op[d] = f2bf(o[d] * inv);
}

// ---- encoder attention: S=50, DH=64, H=6. 128 thr = 2 waves; j-range split
// across waves, LDS partial combine (flash-decoding style).
__global__ __launch_bounds__(128) void attn_enc_kernel(
    const bf16* __restrict__ qkv, bf16* __restrict__ out) {
  const int S = SENC_, H = 6, DH = 64, Dm = H * DH, tri = 3 * Dm;
  int b = blockIdx.x / H, h = blockIdx.x % H;
  int tid = threadIdx.x;
  __shared__ float Ks[SENC_ * 64];
  __shared__ float Vs[SENC_ * 64];
  __shared__ float P1[SENC_ * 66];  // wave-1 partial: o[64], m, l
  const bf16* base = qkv + (long)b * S * tri;
  for (int idx = tid; idx < S * 8; idx += 128) {
    int s = idx >> 3, part = (idx & 7) * 8;
    union { uint4 u; bf16 hh[8]; } kk, vv;
    kk.u = *(const uint4*)(base + (long)s * tri + Dm + h * DH + part);
    vv.u = *(const uint4*)(base + (long)s * tri + 2 * Dm + h * DH + part);
#pragma unroll
    for (int j = 0; j < 8; j++) {
      Ks[s * DH + part + j] = bf2f(kk.hh[j]);
      Vs[s * DH + part + j] = bf2f(vv.hh[j]);
    }
  }
  __syncthreads();
  int w = tid >> 6, lane = tid & 63;
  int row = lane;
  float q[DH], o[DH];
  float m = -1e30f, l = 0.f;
  if (lane < S) {
    const float scale = 0.125f;
#pragma unroll
    for (int d = 0; d < DH; d++) {
      q[d] = bf2f(base[(long)row * tri + h * DH + d]) * scale;
      o[d] = 0.f;
    }
    int jlo = w * 25, jhi = jlo + 25;
    for (int j = jlo; j < jhi; j++) {
      float s = 0.f;
#pragma unroll
      for (int d = 0; d < DH; d++) s += q[d] * Ks[j * DH + d];
      float mn = fmaxf(m, s);
      float corr = __expf(m - mn);
      float p = __expf(s - mn);
      l = l * corr + p;
      m = mn;
#pragma unroll
      for (int d = 0; d < DH; d++) o[d] = o[d] * corr + p * Vs[j * DH + d];
    }
    if (w == 1) {
#pragma unroll
      for (int d = 0; d < DH; d++) P1[row * 66 + d] = o[d];
      P1[row * 66 + 64] = m;
      P1[row * 66 + 65] = l;
    }
  }
  __syncthreads();
  if (w == 0 && lane < S) {
    float m1 = P1[row * 66 + 64], l1 = P1[row * 66 + 65];
    float mg = fmaxf(m, m1);
    float e0 = __expf(m - mg), e1 = __expf(m1 - mg);
    float lg = l * e0 + l1 * e1;
    float inv = 1.f / lg;
    bf16* op = out + ((long)(b * S + row) * Dm + h * DH);
#pragma unroll
    for (int d = 0; d < DH; d++)
      op[d] = f2bf((o[d] * e0 + P1[row * 66 + d] * e1) * inv);
  }
}

// ---------------- small elementwise kernels ----------------
__global__ __launch_bounds__(256) void build_xe_kernel(
    const bf16* __restrict__ vis, const void* __restrict__ cls,
    const void* __restrict__ pos, const int* __restrict__ unmasked,
    float* __restrict__ xe, const int* __restrict__ dflag) {
  int f = *dflag;
  int idx = blockIdx.x * 256 + threadIdx.x;
  const int TOT = B_ * SENC_ * D_;
  if (idx >= TOT) return;
  int d = idx % D_;
  int s = (idx / D_) % SENC_;
  int b = idx / (D_ * SENC_);
  float v;
  if (s == 0) {
    v = rdin(cls, d, f) + rdin(pos, d, f);
  } else {
    int j = s - 1;
    int n = unmasked[b * NVIS_ + j];
    v = bf2f(vis[(long)(b * NVIS_ + j) * D_ + d]) + rdin(pos, (long)(1 + n) * D_ + d, f);
  }
  xe[idx] = v;
}

__global__ __launch_bounds__(256) void dec_init_kernel(
    const void* __restrict__ mask_token, const void* __restrict__ dpos,
    float* __restrict__ full, const int* __restrict__ dflag) {
  int f = *dflag;
  int idx = blockIdx.x * 256 + threadIdx.x;
  const int TOT = B_ * NP_ * DD_;
  if (idx >= TOT) return;
  int d = idx % DD_;
  int n = (idx / DD_) % NP_;
  full[idx] = rdin(mask_token, d, f) + rdin(dpos, (long)(1 + n) * DD_ + d, f);
}

__global__ __launch_bounds__(256) void dec_scatter_kernel(
    const bf16* __restrict__ xd, const int* __restrict__ unmasked,
    const void* __restrict__ dpos, float* __restrict__ full,
    const int* __restrict__ dflag) {
  int f = *dflag;
  int idx = blockIdx.x * 256 + threadIdx.x;
  const int TOT = B_ * NVIS_ * DD_;
  if (idx >= TOT) return;
  int d = idx % DD_;
  int j = (idx / DD_) % NVIS_;
  int b = idx / (DD_ * NVIS_);
  int n = unmasked[b * NVIS_ + j];
  full[((long)(b * NP_ + n)) * DD_ + d] =
      bf2f(xd[((long)(b * SENC_ + 1 + j)) * DD_ + d]) + rdin(dpos, (long)(1 + n) * DD_ + d, f);
}

// ---------------- host ----------------
extern "C" void kernel_launch(void* const* d_in, const int* in_sizes, int n_in,
                              void* d_out, int out_size, void* d_ws, size_t ws_size,
                              hipStream_t stream) {
  (void)in_sizes; (void)n_in;
  const int* unmasked = (const int*)d_in[1];
  const int M_ENC = B_ * SENC_;  // 3200
  const int M_DEC = B_ * NP_;    // 12544
  const int M_VIS = B_ * NVIS_;  // 3136

  // ---- workspace layout (58,884,100 B) ----
  const size_t NEEDED = 58884100;
  if (ws_size < NEEDED) {
    fill_kernel<<<(out_size + 255) / 256, 256, 0, stream>>>(
        (bf16*)d_out, (float)(ws_size >> 20), out_size);
    return;
  }
  char* wsb = (char*)d_ws;
  bf16*  big    = (bf16*)wsb;                 // 12544*1024 bf16 = 25,690,112
  bf16*  t0     = (bf16*)(wsb + 25690112);    // 12544*256  bf16 =  6,422,528
  float* xe     = (float*)(wsb + 32112640);   // 3200*384 f32    =  4,915,200
  float* full   = (float*)(wsb + 37027840);   // 12544*256 f32   = 12,845,056
  bf16*  im2col = (bf16*)(wsb + 49872896);    // 3200*768 bf16   =  4,915,200
  bf16*  vis    = (bf16*)(wsb + 54788096);    // 3200*384 bf16   =  2,457,600
  bf16*  xd     = (bf16*)(wsb + 57245696);    // 3200*256 bf16   =  1,638,400
  int*   dflag  = (int*)(wsb + 58884096);

  probe_kernel<<<1, 64, 0, stream>>>(d_in[3], dflag);

  auto gemm = [&](int mode, const bf16* A, const void* W, long wOff,
                  const void* bias, long bOff, const float* res, void* C,
                  int M, int N, int K, int out_mode) {
    dim3 g(N / 128, M / 128);
    if (mode == 0)
      gemm_kernel<0><<<g, 256, 0, stream>>>(A, W, wOff, bias, bOff, res, C, M, N, K, out_mode, dflag);
    else if (mode == 1)
      gemm_kernel<1><<<g, 256, 0, stream>>>(A, W, wOff, bias, bOff, res, C, M, N, K, out_mode, dflag);
    else
      gemm_kernel<2><<<g, 256, 0, stream>>>(A, W, wOff, bias, bOff, res, C, M, N, K, out_mode, dflag);
  };

  // ---- patchify (visible patches only); im2col rows 3136..3199 are unused
  {
    int tot = M_VIS * 768;
    im2col_vis_kernel<<<(tot + 255) / 256, 256, 0, stream>>>(d_in[0], unmasked, im2col, dflag);
    gemm(0, im2col, d_in[3], 0, d_in[4], 0, nullptr, vis, 3200, D_, 768, 0);
    int tot2 = B_ * SENC_ * D_;
    build_xe_kernel<<<(tot2 + 255) / 256, 256, 0, stream>>>(vis, d_in[5], d_in[6], unmasked, xe, dflag);
  }

  // ---- encoder: 6 blocks, S=50, D=384, H=6, dh=64 ----
  for (int i = 0; i < 6; i++) {
    ln_kernel<D_><<<M_ENC / 4, 256, 0, stream>>>(xe, d_in[7], (long)i * D_, d_in[8], (long)i * D_, t0, M_ENC, dflag);
    gemm(0, t0, d_in[9], (long)i * 3 * D_ * D_, d_in[10], (long)i * 3 * D_, nullptr, big, M_ENC, 3 * D_, D_, 0);
    attn_enc_kernel<<<B_ * 6, 128, 0, stream>>>(big, t0);
    gemm(2, t0, d_in[11], (long)i * D_ * D_, d_in[12], (long)i * D_, xe, xe, M_ENC, D_, D_, 1);
    ln_kernel<D_><<<M_ENC / 4, 256, 0, stream>>>(xe, d_in[13], (long)i * D_, d_in[14], (long)i * D_, t0, M_ENC, dflag);
    gemm(1, t0, d_in[15], (long)i * 4 * D_ * D_, d_in[16], (long)i * 4 * D_, nullptr, big, M_ENC, 4 * D_, D_, 0);
    gemm(2, big, d_in[17], (long)i * D_ * 4 * D_, d_in[18], (long)i * D_, xe, xe, M_ENC, D_, 4 * D_, 1);
  }
  ln_kernel<D_><<<M_ENC / 4, 256, 0, stream>>>(xe, d_in[19], 0, d_in[20], 0, t0, M_ENC, dflag);
  gemm(0, t0, d_in[21], 0, d_in[22], 0, nullptr, xd, M_ENC, DD_, D_, 0);

  // ---- assemble decoder input ----
  {
    int tot = B_ * NP_ * DD_;
    dec_init_kernel<<<(tot + 255) / 256, 256, 0, stream>>>(d_in[23], d_in[24], full, dflag);
    int tot2 = B_ * NVIS_ * DD_;
    dec_scatter_kernel<<<(tot2 + 255) / 256, 256, 0, stream>>>(xd, unmasked, d_in[24], full, dflag);
  }

  // ---- decoder: 4 blocks, S=196, D=256, H=8, dh=32 ----
  for (int i = 0; i < 4; i++) {
    ln_kernel<DD_><<<M_DEC / 4, 256, 0, stream>>>(full, d_in[25], (long)i * DD_, d_in[26], (long)i * DD_, t0, M_DEC, dflag);
    gemm(0, t0, d_in[27], (long)i * 3 * DD_ * DD_, d_in[28], (long)i * 3 * DD_, nullptr, big, M_DEC, 3 * DD_, DD_, 0);
    attn_dec_kernel<<<B_ * 8, 256, 0, stream>>>(big, t0);
    gemm(2, t0, d_in[29], (long)i * DD_ * DD_, d_in[30], (long)i * DD_, full, full, M_DEC, DD_, DD_, 1);
    ln_kernel<DD_><<<M_DEC / 4, 256, 0, stream>>>(full, d_in[31], (long)i * DD_, d_in[32], (long)i * DD_, t0, M_DEC, dflag);
    gemm(1, t0, d_in[33], (long)i * 4 * DD_ * DD_, d_in[34], (long)i * 4 * DD_, nullptr, big, M_DEC, 4 * DD_, DD_, 0);
    gemm(2, big, d_in[35], (long)i * DD_ * 4 * DD_, d_in[36], (long)i * DD_, full, full, M_DEC, DD_, 4 * DD_, 1);
  }
  ln_kernel<DD_><<<M_DEC / 4, 256, 0, stream>>>(full, d_in[37], 0, d_in[38], 0, t0, M_DEC, dflag);

  // ---- predictor head: output dtype follows input dtype ----
  gemm(0, t0, d_in[39], 0, d_in[40], 0, nullptr, d_out, M_DEC, 768, DD_, 2);
}

// Round 5
// 1769.080 us; speedup vs baseline: 3.5899x; 1.3001x over previous
//
#include <hip/hip_runtime.h>
#include <hip/hip_bf16.h>

#define B_    64
#define NP_   196
#define NVIS_ 49
#define D_    384
#define DD_   256
#define SENC_ 50
#define SDEC_ 196

typedef __hip_bfloat16 bf16;
typedef __attribute__((ext_vector_type(8))) short short8;
typedef __attribute__((ext_vector_type(4))) float float4v;

__device__ __forceinline__ float bf2f(bf16 x) { return __bfloat162float(x); }
__device__ __forceinline__ bf16 f2bf(float x) { return __float2bfloat16(x); }
__device__ __forceinline__ float rdin(const void* p, long i, int f) {
  return f ? ((const float*)p)[i] : bf2f(((const bf16*)p)[i]);
}

// ---- dtype probe ----
__global__ void probe_kernel(const void* w, int* flag) {
  int tid = threadIdx.x;
  float mx = 0.f;
  for (int i = tid; i < 512; i += 64)
    mx = fmaxf(mx, fabsf(bf2f(((const bf16*)w)[i])));
#pragma unroll
  for (int off = 32; off; off >>= 1) mx = fmaxf(mx, __shfl_xor(mx, off));
  if (tid == 0) *flag = (mx > 1e3f) ? 1 : 0;  // 1 => inputs are fp32
}

__global__ __launch_bounds__(256) void fill_kernel(bf16* out, float v, int n) {
  int idx = blockIdx.x * 256 + threadIdx.x;
  if (idx < n) out[idx] = f2bf(v);
}

// ---------------- im2col over VISIBLE patches only -> bf16 ----------------
__global__ __launch_bounds__(256) void im2col_vis_kernel(
    const void* __restrict__ x, const int* __restrict__ unmasked,
    bf16* __restrict__ out, const int* __restrict__ dflag) {
  int f = *dflag;
  int idx = blockIdx.x * 256 + threadIdx.x;
  const int TOT = B_ * NVIS_ * 768;
  if (idx >= TOT) return;
  int k = idx % 768;
  int row = idx / 768;
  int j = row % NVIS_;
  int b = row / NVIS_;
  int n = unmasked[b * NVIS_ + j];
  int ph = n / 14, pw = n % 14;
  int c  = k >> 8;
  int rr = (k >> 4) & 15;
  int cc = k & 15;
  out[idx] = f2bf(rdin(x, (long)(((b * 3 + c) * 224) + ph * 16 + rr) * 224 + pw * 16 + cc, f));
}

// ---- MFMA GEMM, tile-configurable: wave tile TMW x TNW, block 2x2 waves ----
// C[M,N] = epi(A[M,K](bf16) @ W[N,K]^T + bias)
// MODE 0 plain, 1 exact GELU, 2 += res(f32).
// out_mode: 0 bf16, 1 f32, 2 per dtype flag. M%(2TMW)==0, N%(2TNW)==0, K%32==0.
#define LDK 40
template <int MODE, int TMW, int TNW>
__global__ __launch_bounds__(256) void gemm_kernel(
    const bf16* __restrict__ A, const void* __restrict__ W, long wOff,
    const void* __restrict__ bias, long bOff, const float* __restrict__ res,
    void* __restrict__ C, int M, int N, int K, int out_mode,
    const int* __restrict__ dflag) {
  constexpr int BM = 2 * TMW, BN = 2 * TNW;
  constexpr int AM = TMW / 16, AN = TNW / 16;
  int f = *dflag;
  __shared__ bf16 Asl[BM * LDK];
  __shared__ bf16 Bsl[BN * LDK];
  int tid = threadIdx.x;
  int bx = blockIdx.x, by = blockIdx.y;
  int w = tid >> 6, lane = tid & 63;
  int quad = lane >> 4, l16 = lane & 15;
  int wm = (w & 1) * TMW, wn = (w >> 1) * TNW;
  int tr = tid >> 2, tc = (tid & 3) * 8;
  const bf16* Ab = A + (long)by * BM * K;
  long wBase = wOff + (long)bx * BN * K;

  float4v acc[AM][AN];
#pragma unroll
  for (int i = 0; i < AM; i++)
#pragma unroll
    for (int j = 0; j < AN; j++) acc[i][j] = (float4v){0.f, 0.f, 0.f, 0.f};

  for (int k0 = 0; k0 < K; k0 += 32) {
#pragma unroll
    for (int h2 = 0; h2 < BM / 64; h2++) {
      int r = tr + h2 * 64;
      uint4 v = *(const uint4*)(Ab + (long)r * K + k0 + tc);
      *(uint4*)(&Asl[r * LDK + tc]) = v;
    }
    if (f) {
#pragma unroll
      for (int h2 = 0; h2 < BN / 64; h2++) {
        int r = tr + h2 * 64;
        const float* p = (const float*)W + wBase + (long)r * K + k0 + tc;
        float4 v0 = *(const float4*)p;
        float4 v1 = *(const float4*)(p + 4);
        union { uint4 u; bf16 hh[8]; } pk;
        pk.hh[0] = f2bf(v0.x); pk.hh[1] = f2bf(v0.y);
        pk.hh[2] = f2bf(v0.z); pk.hh[3] = f2bf(v0.w);
        pk.hh[4] = f2bf(v1.x); pk.hh[5] = f2bf(v1.y);
        pk.hh[6] = f2bf(v1.z); pk.hh[7] = f2bf(v1.w);
        *(uint4*)(&Bsl[r * LDK + tc]) = pk.u;
      }
    } else {
#pragma unroll
      for (int h2 = 0; h2 < BN / 64; h2++) {
        int r = tr + h2 * 64;
        uint4 v = *(const uint4*)((const bf16*)W + wBase + (long)r * K + k0 + tc);
        *(uint4*)(&Bsl[r * LDK + tc]) = v;
      }
    }
    __syncthreads();
    short8 af[AM], bfr[AN];
#pragma unroll
    for (int mi = 0; mi < AM; mi++)
      af[mi] = *(const short8*)&Asl[(wm + mi * 16 + l16) * LDK + quad * 8];
#pragma unroll
    for (int ni = 0; ni < AN; ni++)
      bfr[ni] = *(const short8*)&Bsl[(wn + ni * 16 + l16) * LDK + quad * 8];
#pragma unroll
    for (int mi = 0; mi < AM; mi++)
#pragma unroll
      for (int ni = 0; ni < AN; ni++)
        acc[mi][ni] = __builtin_amdgcn_mfma_f32_16x16x32_bf16(
            af[mi], bfr[ni], acc[mi][ni], 0, 0, 0);
    __syncthreads();
  }

  int om = (out_mode == 2) ? (f ? 1 : 0) : out_mode;  // 1=f32, 0=bf16
#pragma unroll
  for (int mi = 0; mi < AM; mi++) {
#pragma unroll
    for (int ni = 0; ni < AN; ni++) {
      int cn = bx * BN + wn + ni * 16 + l16;
      float bval = rdin(bias, bOff + cn, f);
#pragma unroll
      for (int r = 0; r < 4; r++) {
        int cm = by * BM + wm + mi * 16 + quad * 4 + r;
        float v = acc[mi][ni][r] + bval;
        if constexpr (MODE == 1) v = 0.5f * v * (1.0f + erff(v * 0.70710678f));
        if constexpr (MODE == 2) v += res[(long)cm * N + cn];
        if (om) ((float*)C)[(long)cm * N + cn] = v;
        else    ((bf16*)C)[(long)cm * N + cn] = f2bf(v);
      }
    }
  }
}

// ---------------- LayerNorm: one wave per row, f32 -> bf16 ----------------
template <int N>
__global__ __launch_bounds__(256) void ln_kernel(
    const float* __restrict__ X, const void* __restrict__ w, long wOff,
    const void* __restrict__ bv, long bOff, bf16* __restrict__ Y, int M,
    const int* __restrict__ dflag) {
  int f = *dflag;
  int row = blockIdx.x * 4 + (threadIdx.x >> 6);
  int lane = threadIdx.x & 63;
  if (row >= M) return;
  const float* xr = X + (long)row * N;
  constexpr int CNT = N / 64;
  float v[CNT];
  float sum = 0.f;
#pragma unroll
  for (int i = 0; i < CNT; i++) { v[i] = xr[lane + 64 * i]; sum += v[i]; }
#pragma unroll
  for (int off = 32; off; off >>= 1) sum += __shfl_xor(sum, off);
  float mean = sum * (1.0f / N);
  float vs = 0.f;
#pragma unroll
  for (int i = 0; i < CNT; i++) { float d = v[i] - mean; vs += d * d; }
#pragma unroll
  for (int off = 32; off; off >>= 1) vs += __shfl_xor(vs, off);
  float rstd = rsqrtf(vs * (1.0f / N) + 1e-5f);
  bf16* yr = Y + (long)row * N;
#pragma unroll
  for (int i = 0; i < CNT; i++) {
    int cidx = lane + 64 * i;
    yr[cidx] = f2bf((v[i] - mean) * rstd * rdin(w, wOff + cidx, f) + rdin(bv, bOff + cidx, f));
  }
}

// ---- decoder attention, MFMA flash: S=196, DH=32, H=8 --------------------
// block=(b,h), 4 waves. K(stride 40) + V^T(stride 232) in LDS, Q direct from
// global (row-clamped). Per wave & q-tile: 13 QK^T MFMAs -> softmax (16-lane
// shfl) -> P via per-wave LDS (C-layout -> A-layout) -> 14 PV MFMAs.
__global__ __launch_bounds__(256) void attn_dec_kernel(
    const bf16* __restrict__ qkv, bf16* __restrict__ out) {
  const int S = SDEC_, DH = 32, Dm = 256, tri = 768;
  const int KLD = 40, VLD = 232, PLD = 232;
  int b = blockIdx.x >> 3, h = blockIdx.x & 7;
  __shared__ bf16 Ksh[208 * KLD];
  __shared__ bf16 Vt[32 * VLD];
  __shared__ bf16 Psh[4][16 * PLD];
  int tid = threadIdx.x;
  const bf16* base = qkv + (long)b * S * tri;
  // stage K rows 0..195 (16B chunks), zero rows 196..207
  for (int idx = tid; idx < S * 4; idx += 256) {
    int s = idx >> 2, part = (idx & 3) * 8;
    uint4 v = *(const uint4*)(base + (long)s * tri + Dm + h * DH + part);
    *(uint4*)(&Ksh[s * KLD + part]) = v;
  }
  if (tid < 12 * 4) {
    int s = 196 + (tid >> 2), part = (tid & 3) * 8;
    uint4 z = {0, 0, 0, 0};
    *(uint4*)(&Ksh[s * KLD + part]) = z;
  }
  // stage V transposed; zero cols 196..231
  for (int idx = tid; idx < S * DH; idx += 256) {
    int s = idx >> 5, d = idx & 31;
    Vt[d * VLD + s] = base[(long)s * tri + 2 * Dm + h * DH + d];
  }
  for (int idx = tid; idx < 32 * 36; idx += 256) {
    int d = idx / 36, c = 196 + idx % 36;
    Vt[d * VLD + c] = f2bf(0.f);
  }
  __syncthreads();
  int w = tid >> 6, lane = tid & 63, l16 = lane & 15, quad = lane >> 4;
  bf16* Pw = &Psh[w][0];
  const float scale = 0.17677669529663687f;
  for (int qt = w; qt < 13; qt += 4) {
    int q0 = qt * 16;
    int qr = min(q0 + l16, S - 1);
    short8 qf = *(const short8*)(base + (long)qr * tri + h * DH + quad * 8);
    float4v sc[13];
#pragma unroll
    for (int t = 0; t < 13; t++) {
      short8 kf = *(const short8*)&Ksh[(t * 16 + l16) * KLD + quad * 8];
      sc[t] = __builtin_amdgcn_mfma_f32_16x16x32_bf16(
          qf, kf, (float4v){0.f, 0.f, 0.f, 0.f}, 0, 0, 0);
    }
    float mx[4] = {-1e30f, -1e30f, -1e30f, -1e30f};
#pragma unroll
    for (int t = 0; t < 13; t++) {
      bool valid = (t * 16 + l16) < S;
#pragma unroll
      for (int r = 0; r < 4; r++) {
        float v = valid ? sc[t][r] * scale : -1e30f;
        sc[t][r] = v;
        mx[r] = fmaxf(mx[r], v);
      }
    }
#pragma unroll
    for (int off = 1; off < 16; off <<= 1)
#pragma unroll
      for (int r = 0; r < 4; r++) mx[r] = fmaxf(mx[r], __shfl_xor(mx[r], off));
    float sm[4] = {0.f, 0.f, 0.f, 0.f};
#pragma unroll
    for (int t = 0; t < 13; t++)
#pragma unroll
      for (int r = 0; r < 4; r++) {
        float p = __expf(sc[t][r] - mx[r]);
        sc[t][r] = p;
        sm[r] += p;
      }
#pragma unroll
    for (int off = 1; off < 16; off <<= 1)
#pragma unroll
      for (int r = 0; r < 4; r++) sm[r] += __shfl_xor(sm[r], off);
    // P: C-layout regs -> LDS [row][col]; cols 208..223 zeroed (t==13)
#pragma unroll
    for (int t = 0; t < 14; t++) {
      int col = t * 16 + l16;
#pragma unroll
      for (int r = 0; r < 4; r++) {
        float p = (t < 13) ? sc[t][r] : 0.f;
        Pw[(quad * 4 + r) * PLD + col] = f2bf(p);
      }
    }
    __asm__ volatile("s_waitcnt lgkmcnt(0)" ::: "memory");
    float4v o0 = {0.f, 0.f, 0.f, 0.f}, o1 = {0.f, 0.f, 0.f, 0.f};
#pragma unroll
    for (int kc = 0; kc < 7; kc++) {
      short8 pf = *(const short8*)&Pw[l16 * PLD + kc * 32 + quad * 8];
      short8 v0 = *(const short8*)&Vt[l16 * VLD + kc * 32 + quad * 8];
      short8 v1 = *(const short8*)&Vt[(16 + l16) * VLD + kc * 32 + quad * 8];
      o0 = __builtin_amdgcn_mfma_f32_16x16x32_bf16(pf, v0, o0, 0, 0, 0);
      o1 = __builtin_amdgcn_mfma_f32_16x16x32_bf16(pf, v1, o1, 0, 0, 0);
    }
#pragma unroll
    for (int r = 0; r < 4; r++) {
      int row = q0 + quad * 4 + r;
      if (row < S) {
        float inv = 1.f / sm[r];
        bf16* op = out + ((long)(b * S + row)) * Dm + h * DH;
        op[l16]      = f2bf(o0[r] * inv);
        op[16 + l16] = f2bf(o1[r] * inv);
      }
    }
  }
}

// ---- encoder attention: S=50, DH=64, H=6. 128 thr = 2 waves, j-split ------
__global__ __launch_bounds__(128) void attn_enc_kernel(
    const bf16* __restrict__ qkv, bf16* __restrict__ out) {
  const int S = SENC_, H = 6, DH = 64, Dm = H * DH, tri = 3 * Dm;
  int b = blockIdx.x / H, h = blockIdx.x % H;
  int tid = threadIdx.x;
  __shared__ float Ks[SENC_ * 64];
  __shared__ float Vs[SENC_ * 64];
  __shared__ float P1[SENC_ * 66];
  const bf16* base = qkv + (long)b * S * tri;
  for (int idx = tid; idx < S * 8; idx += 128) {
    int s = idx >> 3, part = (idx & 7) * 8;
    union { uint4 u; bf16 hh[8]; } kk, vv;
    kk.u = *(const uint4*)(base + (long)s * tri + Dm + h * DH + part);
    vv.u = *(const uint4*)(base + (long)s * tri + 2 * Dm + h * DH + part);
#pragma unroll
    for (int j = 0; j < 8; j++) {
      Ks[s * DH + part + j] = bf2f(kk.hh[j]);
      Vs[s * DH + part + j] = bf2f(vv.hh[j]);
    }
  }
  __syncthreads();
  int w = tid >> 6, lane = tid & 63;
  int row = lane;
  float q[DH], o[DH];
  float m = -1e30f, l = 0.f;
  if (lane < S) {
    const float scale = 0.125f;
#pragma unroll
    for (int d = 0; d < DH; d++) {
      q[d] = bf2f(base[(long)row * tri + h * DH + d]) * scale;
      o[d] = 0.f;
    }
    int jlo = w * 25, jhi = jlo + 25;
    for (int j = jlo; j < jhi; j++) {
      float s = 0.f;
#pragma unroll
      for (int d = 0; d < DH; d++) s += q[d] * Ks[j * DH + d];
      float mn = fmaxf(m, s);
      float corr = __expf(m - mn);
      float p = __expf(s - mn);
      l = l * corr + p;
      m = mn;
#pragma unroll
      for (int d = 0; d < DH; d++) o[d] = o[d] * corr + p * Vs[j * DH + d];
    }
    if (w == 1) {
#pragma unroll
      for (int d = 0; d < DH; d++) P1[row * 66 + d] = o[d];
      P1[row * 66 + 64] = m;
      P1[row * 66 + 65] = l;
    }
  }
  __syncthreads();
  if (w == 0 && lane < S) {
    float m1 = P1[row * 66 + 64], l1 = P1[row * 66 + 65];
    float mg = fmaxf(m, m1);
    float e0 = __expf(m - mg), e1 = __expf(m1 - mg);
    float lg = l * e0 + l1 * e1;
    float inv = 1.f / lg;
    bf16* op = out + ((long)(b * S + row) * Dm + h * DH);
#pragma unroll
    for (int d = 0; d < DH; d++)
      op[d] = f2bf((o[d] * e0 + P1[row * 66 + d] * e1) * inv);
  }
}

// ---------------- small elementwise kernels ----------------
__global__ __launch_bounds__(256) void build_xe_kernel(
    const bf16* __restrict__ vis, const void* __restrict__ cls,
    const void* __restrict__ pos, const int* __restrict__ unmasked,
    float* __restrict__ xe, const int* __restrict__ dflag) {
  int f = *dflag;
  int idx = blockIdx.x * 256 + threadIdx.x;
  const int TOT = B_ * SENC_ * D_;
  if (idx >= TOT) return;
  int d = idx % D_;
  int s = (idx / D_) % SENC_;
  int b = idx / (D_ * SENC_);
  float v;
  if (s == 0) {
    v = rdin(cls, d, f) + rdin(pos, d, f);
  } else {
    int j = s - 1;
    int n = unmasked[b * NVIS_ + j];
    v = bf2f(vis[(long)(b * NVIS_ + j) * D_ + d]) + rdin(pos, (long)(1 + n) * D_ + d, f);
  }
  xe[idx] = v;
}

__global__ __launch_bounds__(256) void dec_init_kernel(
    const void* __restrict__ mask_token, const void* __restrict__ dpos,
    float* __restrict__ full, const int* __restrict__ dflag) {
  int f = *dflag;
  int idx = blockIdx.x * 256 + threadIdx.x;
  const int TOT = B_ * NP_ * DD_;
  if (idx >= TOT) return;
  int d = idx % DD_;
  int n = (idx / DD_) % NP_;
  full[idx] = rdin(mask_token, d, f) + rdin(dpos, (long)(1 + n) * DD_ + d, f);
}

__global__ __launch_bounds__(256) void dec_scatter_kernel(
    const bf16* __restrict__ xd, const int* __restrict__ unmasked,
    const void* __restrict__ dpos, float* __restrict__ full,
    const int* __restrict__ dflag) {
  int f = *dflag;
  int idx = blockIdx.x * 256 + threadIdx.x;
  const int TOT = B_ * NVIS_ * DD_;
  if (idx >= TOT) return;
  int d = idx % DD_;
  int j = (idx / DD_) % NVIS_;
  int b = idx / (DD_ * NVIS_);
  int n = unmasked[b * NVIS_ + j];
  full[((long)(b * NP_ + n)) * DD_ + d] =
      bf2f(xd[((long)(b * SENC_ + 1 + j)) * DD_ + d]) + rdin(dpos, (long)(1 + n) * DD_ + d, f);
}

// ---------------- host ----------------
extern "C" void kernel_launch(void* const* d_in, const int* in_sizes, int n_in,
                              void* d_out, int out_size, void* d_ws, size_t ws_size,
                              hipStream_t stream) {
  (void)in_sizes; (void)n_in;
  const int* unmasked = (const int*)d_in[1];
  const int M_ENC = B_ * SENC_;  // 3200
  const int M_DEC = B_ * NP_;    // 12544
  const int M_VIS = B_ * NVIS_;  // 3136

  const size_t NEEDED = 58884100;
  if (ws_size < NEEDED) {
    fill_kernel<<<(out_size + 255) / 256, 256, 0, stream>>>(
        (bf16*)d_out, (float)(ws_size >> 20), out_size);
    return;
  }
  char* wsb = (char*)d_ws;
  bf16*  big    = (bf16*)wsb;                 // 12544*1024 bf16 = 25,690,112
  bf16*  t0     = (bf16*)(wsb + 25690112);    // 12544*256  bf16 =  6,422,528
  float* xe     = (float*)(wsb + 32112640);   // 3200*384 f32    =  4,915,200
  float* full   = (float*)(wsb + 37027840);   // 12544*256 f32   = 12,845,056
  bf16*  im2col = (bf16*)(wsb + 49872896);    // 3200*768 bf16   =  4,915,200
  bf16*  vis    = (bf16*)(wsb + 54788096);    // 3200*384 bf16   =  2,457,600
  bf16*  xd     = (bf16*)(wsb + 57245696);    // 3200*256 bf16   =  1,638,400
  int*   dflag  = (int*)(wsb + 58884096);

  probe_kernel<<<1, 64, 0, stream>>>(d_in[3], dflag);

  // cfg: 0 -> 128x128 tile, 1 -> 128x64, 2 -> 64x64
  auto gemm = [&](int mode, int cfg, const bf16* A, const void* W, long wOff,
                  const void* bias, long bOff, const float* res, void* C,
                  int M, int N, int K, int out_mode) {
    int BM = (cfg == 2) ? 64 : 128;
    int BN = (cfg == 0) ? 128 : 64;
    dim3 g(N / BN, M / BM);
#define GL(MO, TM, TN) gemm_kernel<MO, TM, TN><<<g, 256, 0, stream>>>( \
        A, W, wOff, bias, bOff, res, C, M, N, K, out_mode, dflag)
    if (mode == 0) {
      if (cfg == 0) GL(0, 64, 64); else if (cfg == 1) GL(0, 64, 32); else GL(0, 32, 32);
    } else if (mode == 1) {
      if (cfg == 0) GL(1, 64, 64); else if (cfg == 1) GL(1, 64, 32); else GL(1, 32, 32);
    } else {
      if (cfg == 0) GL(2, 64, 64); else if (cfg == 1) GL(2, 64, 32); else GL(2, 32, 32);
    }
#undef GL
  };

  // ---- patchify (visible patches only); im2col rows 3136..3199 unused ----
  {
    int tot = M_VIS * 768;
    im2col_vis_kernel<<<(tot + 255) / 256, 256, 0, stream>>>(d_in[0], unmasked, im2col, dflag);
    gemm(0, 2, im2col, d_in[3], 0, d_in[4], 0, nullptr, vis, 3200, D_, 768, 0);
    int tot2 = B_ * SENC_ * D_;
    build_xe_kernel<<<(tot2 + 255) / 256, 256, 0, stream>>>(vis, d_in[5], d_in[6], unmasked, xe, dflag);
  }

  // ---- encoder: 6 blocks, S=50, D=384, H=6, dh=64 ----
  for (int i = 0; i < 6; i++) {
    ln_kernel<D_><<<M_ENC / 4, 256, 0, stream>>>(xe, d_in[7], (long)i * D_, d_in[8], (long)i * D_, t0, M_ENC, dflag);
    gemm(0, 1, t0, d_in[9], (long)i * 3 * D_ * D_, d_in[10], (long)i * 3 * D_, nullptr, big, M_ENC, 3 * D_, D_, 0);
    attn_enc_kernel<<<B_ * 6, 128, 0, stream>>>(big, t0);
    gemm(2, 2, t0, d_in[11], (long)i * D_ * D_, d_in[12], (long)i * D_, xe, xe, M_ENC, D_, D_, 1);
    ln_kernel<D_><<<M_ENC / 4, 256, 0, stream>>>(xe, d_in[13], (long)i * D_, d_in[14], (long)i * D_, t0, M_ENC, dflag);
    gemm(1, 0, t0, d_in[15], (long)i * 4 * D_ * D_, d_in[16], (long)i * 4 * D_, nullptr, big, M_ENC, 4 * D_, D_, 0);
    gemm(2, 2, big, d_in[17], (long)i * D_ * 4 * D_, d_in[18], (long)i * D_, xe, xe, M_ENC, D_, 4 * D_, 1);
  }
  ln_kernel<D_><<<M_ENC / 4, 256, 0, stream>>>(xe, d_in[19], 0, d_in[20], 0, t0, M_ENC, dflag);
  gemm(0, 2, t0, d_in[21], 0, d_in[22], 0, nullptr, xd, M_ENC, DD_, D_, 0);

  // ---- assemble decoder input ----
  {
    int tot = B_ * NP_ * DD_;
    dec_init_kernel<<<(tot + 255) / 256, 256, 0, stream>>>(d_in[23], d_in[24], full, dflag);
    int tot2 = B_ * NVIS_ * DD_;
    dec_scatter_kernel<<<(tot2 + 255) / 256, 256, 0, stream>>>(xd, unmasked, d_in[24], full, dflag);
  }

  // ---- decoder: 4 blocks, S=196, D=256, H=8, dh=32 ----
  for (int i = 0; i < 4; i++) {
    ln_kernel<DD_><<<M_DEC / 4, 256, 0, stream>>>(full, d_in[25], (long)i * DD_, d_in[26], (long)i * DD_, t0, M_DEC, dflag);
    gemm(0, 0, t0, d_in[27], (long)i * 3 * DD_ * DD_, d_in[28], (long)i * 3 * DD_, nullptr, big, M_DEC, 3 * DD_, DD_, 0);
    attn_dec_kernel<<<B_ * 8, 256, 0, stream>>>(big, t0);
    gemm(2, 1, t0, d_in[29], (long)i * DD_ * DD_, d_in[30], (long)i * DD_, full, full, M_DEC, DD_, DD_, 1);
    ln_kernel<DD_><<<M_DEC / 4, 256, 0, stream>>>(full, d_in[31], (long)i * DD_, d_in[32], (long)i * DD_, t0, M_DEC, dflag);
    gemm(1, 0, t0, d_in[33], (long)i * 4 * DD_ * DD_, d_in[34], (long)i * 4 * DD_, nullptr, big, M_DEC, 4 * DD_, DD_, 0);
    gemm(2, 1, big, d_in[35], (long)i * DD_ * 4 * DD_, d_in[36], (long)i * DD_, full, full, M_DEC, DD_, 4 * DD_, 1);
  }
  ln_kernel<DD_><<<M_DEC / 4, 256, 0, stream>>>(full, d_in[37], 0, d_in[38], 0, t0, M_DEC, dflag);

  // ---- predictor head: output dtype follows input dtype ----
  gemm(0, 0, t0, d_in[39], 0, d_in[40], 0, nullptr, d_out, M_DEC, 768, DD_, 2);
}